// Round 4
// baseline (1070.943 us; speedup 1.0000x reference)
//
#include <hip/hip_runtime.h>

#define H 512
#define TSTEPS 196
#define FLEN 784
#define NBATCH 256

typedef float f4 __attribute__((ext_vector_type(4)));

// ws float layout — each weight matrix is a 513-column slot (512 real columns
// transposed + 1 zero column used as the gather pad target):
//   slot stride = 513*512 = 262656 floats
//   [0)        WT_h2h1 (cols 0..511), zeros at [262144..262656)
//   [262656)   WT_i2h2 + zeros
//   [525312)   WT_h2h2 + zeros
//   [787968)   WT_i2h3 + zeros
//   [1050624)  m1T [196][512]
//   [1150976)  m2T
//   [1251328)  m3T      (end 1351680 floats = 5.41 MB)
#define SLOT 262656
#define MBASE 1050624
#define PADOFF (512 << 11)   // byte offset of the zero column within a slot

__global__ void transpose4(const float* __restrict__ a,
                           const float* __restrict__ b,
                           const float* __restrict__ c,
                           const float* __restrict__ d,
                           float* __restrict__ ws)
{
    __shared__ float tile[32][33];
    const float* src = (blockIdx.z == 0) ? a : (blockIdx.z == 1) ? b
                     : (blockIdx.z == 2) ? c : d;
    float* dst = ws + (size_t)blockIdx.z * SLOT;
    int bx = blockIdx.x * 32, by = blockIdx.y * 32;
    int tx = threadIdx.x, ty = threadIdx.y;
    for (int r = ty; r < 32; r += 8)
        tile[r][tx] = src[(by + r) * H + bx + tx];
    __syncthreads();
    for (int r = ty; r < 32; r += 8)
        dst[(bx + r) * H + by + tx] = tile[tx][r];
}

// z<3: transpose masks; z==3: zero the 4 pad columns
__global__ void maskT3(const float* __restrict__ m1, const float* __restrict__ m2,
                       const float* __restrict__ m3, float* __restrict__ ws)
{
    int idx = blockIdx.x * 256 + threadIdx.x;
    int z = blockIdx.z;
    if (z == 3) {
        if (idx < 4 * H) {
            int r = idx >> 9, pos = idx & (H - 1);
            ws[(size_t)r * SLOT + H * H + pos] = 0.0f;
        }
        return;
    }
    if (idx >= TSTEPS * H) return;
    const float* src = (z == 0) ? m1 : (z == 1) ? m2 : m3;
    ws[MBASE + (size_t)z * (TSTEPS * H) + idx] = src[(idx & (H - 1)) * FLEN + (idx >> 9)];
}

// sum of WT columns list[lo..hi) (byte offsets), this thread's float4 slice.
// lo/hi are multiples of 8 (lists are zero-column-padded) -> no tail code.
__device__ __forceinline__ f4 gatherv(const char* __restrict__ wsb, unsigned bias,
                                      const int* __restrict__ list, int lo, int hi)
{
    f4 a0 = (f4)0.0f, a1 = (f4)0.0f, a2 = (f4)0.0f, a3 = (f4)0.0f;
    for (int i = lo; i < hi; i += 8) {
        int4 la = *(const int4*)(list + i);
        int4 lb = *(const int4*)(list + i + 4);
        f4 w0 = *(const f4*)(wsb + ((unsigned)la.x + bias));
        f4 w1 = *(const f4*)(wsb + ((unsigned)la.y + bias));
        f4 w2 = *(const f4*)(wsb + ((unsigned)la.z + bias));
        f4 w3 = *(const f4*)(wsb + ((unsigned)la.w + bias));
        f4 w4 = *(const f4*)(wsb + ((unsigned)lb.x + bias));
        f4 w5 = *(const f4*)(wsb + ((unsigned)lb.y + bias));
        f4 w6 = *(const f4*)(wsb + ((unsigned)lb.z + bias));
        f4 w7 = *(const f4*)(wsb + ((unsigned)lb.w + bias));
        a0 += w0; a1 += w1; a2 += w2; a3 += w3;
        a0 += w4; a1 += w5; a2 += w6; a3 += w7;
    }
    return (a0 + a1) + (a2 + a3);
}

__device__ __forceinline__ float sum8(const float* __restrict__ p, int j)
{
    float s0 = p[j] + p[512 + j];
    float s1 = p[1024 + j] + p[1536 + j];
    float s2 = p[2048 + j] + p[2560 + j];
    float s3 = p[3072 + j] + p[3584 + j];
    return (s0 + s1) + (s2 + s3);
}

__global__ __launch_bounds__(1024)
void lsnn_main(const float* __restrict__ x,
               const float* __restrict__ Wi1,
               const float* __restrict__ bi1, const float* __restrict__ bh1,
               const float* __restrict__ bi2, const float* __restrict__ bh2,
               const float* __restrict__ bi3,
               const float* __restrict__ Wo,  const float* __restrict__ bo,
               const float* __restrict__ tau1, const float* __restrict__ tau2,
               const float* __restrict__ tau3,
               const float* __restrict__ ws,
               float* __restrict__ out)
{
    const char*  wsb = (const char*)ws;
    const float* m1T = ws + MBASE;
    const float* m2T = m1T + TSTEPS * H;
    const float* m3T = m2T + TSTEPS * H;

    const int n    = blockIdx.x;
    const int tid  = threadIdx.x;
    const int j    = tid & (H - 1);
    const int jq   = tid & 127;          // float4-slice id within a column
    const int grp  = tid >> 7;           // gather group 0..7
    const int lane = tid & 63;
    const int wid8 = (tid >> 6) & 7;
    const bool upd = tid < 512;

    const unsigned jb   = (unsigned)jq << 4;      // byte offset of slice
    const unsigned b_h1 = 0u * SLOT * 4u + jb;
    const unsigned b_i2 = 1u * SLOT * 4u + jb;
    const unsigned b_h2 = 2u * SLOT * 4u + jb;
    const unsigned b_i3 = 3u * SLOT * 4u + jb;

    __shared__ int  list1[H], list2[H];
    __shared__ f4   part[3][8][128];     // per-layer rotating partial buffers
    __shared__ f4   pH[4][128];          // helper-half h2h2 partials
    __shared__ int  wcnt[8];

    float4 wi = reinterpret_cast<const float4*>(Wi1)[j];
    float bs1 = bi1[j] + bh1[j];
    float bs2 = bi2[j] + bh2[j];
    float bs3 = bi3[j];
    float ro1 = expf(-1.0f / tau1[j]);
    float ro2 = expf(-1.0f / tau2[j]);
    float ro3 = expf(-1.0f / tau3[j]);
    float omr1 = 1.0f - ro1, omr2 = 1.0f - ro2, omr3 = 1.0f - ro3;
    const float alpha = expf(-1.0f / 20.0f);
    const float oma = 1.0f - alpha;

    float mem1 = 0.f, mem2 = 0.f, mem3 = 0.f;
    float b1 = 0.01f, b2 = 0.01f, b3 = 0.01f;
    float s1 = 0.f, s2 = 0.f, s3 = 0.f;
    float cnt3 = 0.f;
    int na1 = 0, nap1 = 0, na2 = 0, nap2 = 0;

    const float* xr = x + n * FLEN;

    for (int t = 0; t < TSTEPS; ++t) {
        int base = (t < 48) ? (4 * t) : (FLEN - 4);
        float4 xv = *reinterpret_cast<const float4*>(xr + base);
        float mk1 = m1T[t * H + j];
        float mk2 = m2T[t * H + j];
        float mk3 = m3T[t * H + j];

        // ---- gather1: s1_old @ Wh1^T (all 8 groups) ----
        {
            int ch = nap1 >> 3;
            part[0][grp][jq] = gatherv(wsb, b_h1, list1, grp * ch, (grp + 1) * ch);
        }
        __syncthreads();                                        // B1
        unsigned long long ball = 0;
        if (upd) {
            // ---- layer-1 update ----
            float h1 = wi.x * xv.x + wi.y * xv.y + wi.z * xv.z + wi.w * xv.w
                     + bs1 + sum8((const float*)&part[0][0][0], j);
            b1 = ro1 * b1 + omr1 * s1;
            float Bth = 0.01f + 1.8f * b1;
            float nm = mem1 * alpha + oma * h1 - Bth * s1;
            mem1 = (mk1 == 0.0f) ? mem1 : nm;
            s1 = (mem1 - Bth > 0.0f) ? mk1 : 0.0f;
            ball = __ballot(s1 != 0.0f);
            if (lane == 0) wcnt[wid8] = __popcll(ball);
        } else {
            // ---- overlapped: s2_old @ Wh2^T (helper half, 4 groups) ----
            int q = grp - 4, ch = nap2 >> 2;
            pH[q][jq] = gatherv(wsb, b_h2, list2, q * ch, (q + 1) * ch);
        }
        __syncthreads();                                        // B2
        {
            int basew = 0, tot = 0;
#pragma unroll
            for (int w = 0; w < 8; ++w) {
                int c = wcnt[w];
                if (w < wid8) basew += c;
                tot += c;
            }
            if (upd && s1 != 0.0f) {
                int pre = __popcll(ball & ((1ull << lane) - 1ull));
                list1[basew + pre] = j << 11;
            }
            na1 = tot;
            nap1 = (na1 + 63) & ~63;
            if (tid < nap1 - na1) list1[na1 + tid] = PADOFF;
        }
        __syncthreads();                                        // B3

        // ---- gather2: s1_new @ Wi2^T (all 8 groups) ----
        {
            int ch = nap1 >> 3;
            part[1][grp][jq] = gatherv(wsb, b_i2, list1, grp * ch, (grp + 1) * ch);
        }
        __syncthreads();                                        // B4
        if (upd) {
            // ---- layer-2 update ----
            const float* ph = (const float*)&pH[0][0];
            float gh = (ph[j] + ph[512 + j]) + (ph[1024 + j] + ph[1536 + j]);
            float h2 = bs2 + sum8((const float*)&part[1][0][0], j) + gh;
            b2 = ro2 * b2 + omr2 * s2;
            float Bth = 0.01f + 1.8f * b2;
            float nm = mem2 * alpha + oma * h2 - Bth * s2;
            mem2 = (mk2 == 0.0f) ? mem2 : nm;
            s2 = (mem2 - Bth > 0.0f) ? mk2 : 0.0f;
            ball = __ballot(s2 != 0.0f);
            if (lane == 0) wcnt[wid8] = __popcll(ball);
        }
        __syncthreads();                                        // B5
        {
            int basew = 0, tot = 0;
#pragma unroll
            for (int w = 0; w < 8; ++w) {
                int c = wcnt[w];
                if (w < wid8) basew += c;
                tot += c;
            }
            if (upd && s2 != 0.0f) {
                int pre = __popcll(ball & ((1ull << lane) - 1ull));
                list2[basew + pre] = j << 11;
            }
            na2 = tot;
            nap2 = (na2 + 63) & ~63;
            if (tid < nap2 - na2) list2[na2 + tid] = PADOFF;
        }
        __syncthreads();                                        // B6

        // ---- gather3: s2_new @ Wi3^T (all 8 groups) ----
        {
            int ch = nap2 >> 3;
            part[2][grp][jq] = gatherv(wsb, b_i3, list2, grp * ch, (grp + 1) * ch);
        }
        __syncthreads();                                        // B7
        if (upd) {
            // ---- layer-3 update ----
            float h3 = bs3 + sum8((const float*)&part[2][0][0], j);
            b3 = ro3 * b3 + omr3 * s3;
            float Bth = 0.01f + 1.8f * b3;
            float nm = mem3 * alpha + oma * h3 - Bth * s3;
            mem3 = (mk3 == 0.0f) ? mem3 : nm;
            s3 = (mem3 - Bth > 0.0f) ? mk3 : 0.0f;
            cnt3 += s3;   // defer output GEMV
        }
        // next step's gather1 writes part[0]; its last read was before B2 — safe.
    }

    // ---- output: out[n,o] = (Wo[o,:]·cnt3 + T*bo[o]) / T ----
    float* c3 = (float*)&part[0][0][0];
    if (upd) c3[j] = cnt3;
    __syncthreads();
    int wv = tid >> 6;   // 0..15
    for (int o = wv; o < 10; o += 16) {
        float p = 0.0f;
        for (int i = lane; i < H; i += 64)
            p += Wo[o * H + i] * c3[i];
        for (int off = 32; off > 0; off >>= 1)
            p += __shfl_down(p, off);
        if (lane == 0)
            out[n * 10 + o] = (p + 196.0f * bo[o]) / 196.0f;
    }
}

extern "C" void kernel_launch(void* const* d_in, const int* in_sizes, int n_in,
                              void* d_out, int out_size, void* d_ws, size_t ws_size,
                              hipStream_t stream)
{
    const float* x    = (const float*)d_in[0];
    const float* Wi1  = (const float*)d_in[1];
    const float* bi1  = (const float*)d_in[2];
    const float* Wh1  = (const float*)d_in[3];
    const float* bh1  = (const float*)d_in[4];
    const float* Wi2  = (const float*)d_in[5];
    const float* bi2  = (const float*)d_in[6];
    const float* Wh2  = (const float*)d_in[7];
    const float* bh2  = (const float*)d_in[8];
    const float* Wi3  = (const float*)d_in[9];
    const float* bi3  = (const float*)d_in[10];
    const float* Wo   = (const float*)d_in[11];
    const float* bo   = (const float*)d_in[12];
    const float* tau1 = (const float*)d_in[13];
    const float* tau2 = (const float*)d_in[14];
    const float* tau3 = (const float*)d_in[15];
    const float* m1   = (const float*)d_in[16];
    const float* m2   = (const float*)d_in[17];
    const float* m3   = (const float*)d_in[18];

    float* ws  = (float*)d_ws;
    float* out = (float*)d_out;

    // pre-pass: transpose 4 matrices into 513-col slots; masks + pad columns
    transpose4<<<dim3(16, 16, 4), dim3(32, 8, 1), 0, stream>>>(Wh1, Wi2, Wh2, Wi3, ws);
    maskT3<<<dim3((TSTEPS * H + 255) / 256, 1, 4), 256, 0, stream>>>(m1, m2, m3, ws);

    // main persistent kernel: 1 sample per workgroup (256 WGs, 1024 thr, 16 waves)
    lsnn_main<<<NBATCH, 1024, 0, stream>>>(x, Wi1, bi1, bh1, bi2, bh2, bi3,
                                           Wo, bo, tau1, tau2, tau3, ws, out);
}

// Round 6
// 741.693 us; speedup vs baseline: 1.4439x; 1.4439x over previous
//
#include <hip/hip_runtime.h>

#define H 512
#define TSTEPS 196
#define FLEN 784
#define NBATCH 256

typedef float f4 __attribute__((ext_vector_type(4)));

// ws float layout:
//   [0)        WT_h2h1  512*512   (WT[k*512+j] = W[j*512+k])
//   [262144)   WT_i2h2  512*512
//   [524288)   WT_h2h2  512*512
//   [786432)   WT_i2h3  512*512
//   [1048576)  m1T      196*512   (mT[t*512+j] = m[j*784+t])
//   [1148928)  m2T      196*512
//   [1249280)  m3T      196*512

__global__ void transpose4(const float* __restrict__ a,
                           const float* __restrict__ b,
                           const float* __restrict__ c,
                           const float* __restrict__ d,
                           float* __restrict__ ws)
{
    __shared__ float tile[32][33];
    const float* src = (blockIdx.z == 0) ? a : (blockIdx.z == 1) ? b
                     : (blockIdx.z == 2) ? c : d;
    float* dst = ws + (size_t)blockIdx.z * (H * H);
    int bx = blockIdx.x * 32, by = blockIdx.y * 32;
    int tx = threadIdx.x, ty = threadIdx.y;
    for (int r = ty; r < 32; r += 8)
        tile[r][tx] = src[(by + r) * H + bx + tx];
    __syncthreads();
    for (int r = ty; r < 32; r += 8)
        dst[(bx + r) * H + by + tx] = tile[tx][r];
}

__global__ void maskT3(const float* __restrict__ m1, const float* __restrict__ m2,
                       const float* __restrict__ m3, float* __restrict__ mt)
{
    int idx = blockIdx.x * 256 + threadIdx.x;
    if (idx >= TSTEPS * H) return;
    const float* src = (blockIdx.z == 0) ? m1 : (blockIdx.z == 1) ? m2 : m3;
    float* dst = mt + (size_t)blockIdx.z * (TSTEPS * H);
    int t = idx >> 9, j = idx & (H - 1);
    dst[idx] = src[j * FLEN + t];
}

// Quad gather: this thread owns rows [4u..4u+3] (WTq pre-biased by 4u).
// Sums float4 rows of columns list[lo..hi) (list holds k<<9 float offsets).
// 4 independent f4 accumulators; tail <=3 iters, group-uniform branch.
__device__ __forceinline__ f4 gatherq(const float* __restrict__ WTq,
                                      const int* __restrict__ list,
                                      int lo, int hi)
{
    f4 a0 = (f4)0.0f, a1 = (f4)0.0f, a2 = (f4)0.0f, a3 = (f4)0.0f;
    int i = lo;
    for (; i + 4 <= hi; i += 4) {
        int k0 = list[i], k1 = list[i + 1], k2 = list[i + 2], k3 = list[i + 3];
        a0 += *(const f4*)(WTq + k0);
        a1 += *(const f4*)(WTq + k1);
        a2 += *(const f4*)(WTq + k2);
        a3 += *(const f4*)(WTq + k3);
    }
    for (; i < hi; ++i)
        a0 += *(const f4*)(WTq + list[i]);
    return (a0 + a1) + (a2 + a3);
}

__device__ __forceinline__ float sumg(const float* __restrict__ p, int j, int ng)
{
    float s = 0.0f;
    for (int gg = 0; gg < ng; ++gg)
        s += p[gg * H + j];
    return s;
}

__global__ __launch_bounds__(1024)
void lsnn_main(const float* __restrict__ x,
               const float* __restrict__ Wi1,
               const float* __restrict__ bi1, const float* __restrict__ bh1,
               const float* __restrict__ bi2, const float* __restrict__ bh2,
               const float* __restrict__ bi3,
               const float* __restrict__ Wo,  const float* __restrict__ bo,
               const float* __restrict__ tau1, const float* __restrict__ tau2,
               const float* __restrict__ tau3,
               const float* __restrict__ ws,
               float* __restrict__ out)
{
    const float* m1T = ws + 1048576;
    const float* m2T = m1T + TSTEPS * H;
    const float* m3T = m2T + TSTEPS * H;

    const int n    = blockIdx.x;
    const int tid  = threadIdx.x;
    const int j    = tid & (H - 1);
    const int lane = tid & 63;
    const int wid8 = (tid >> 6) & 7;     // wave id within 512-thread half
    const bool upd = tid < 512;
    const int u    = tid & 127;          // quad id (rows 4u..4u+3)
    const int g    = tid >> 7;           // gather group 0..7
    const int q4   = g & 3;              // helper quarter (groups 4..7)

    // pre-biased quad pointers
    const float* WT1q  = ws +           (u << 2);   // W_h2h1^T
    const float* WTi2q = ws + 262144 + (u << 2);    // W_i2h2^T
    const float* WTh2q = ws + 524288 + (u << 2);    // W_h2h2^T
    const float* WTi3q = ws + 786432 + (u << 2);    // W_i2h3^T

    __shared__ int list1[H], list2[H];
    __shared__ f4  part[3][8][128];      // rotating partial buffers G1/G2/G3
    __shared__ f4  pH[4][128];           // helper-overlap Wh2 partials
    __shared__ int wcnt[8];

    float4 wi = reinterpret_cast<const float4*>(Wi1)[j];
    float bs1 = bi1[j] + bh1[j];
    float bs2 = bi2[j] + bh2[j];
    float bs3 = bi3[j];
    float ro1 = expf(-1.0f / tau1[j]);
    float ro2 = expf(-1.0f / tau2[j]);
    float ro3 = expf(-1.0f / tau3[j]);
    float omr1 = 1.0f - ro1, omr2 = 1.0f - ro2, omr3 = 1.0f - ro3;
    const float alpha = expf(-1.0f / 20.0f);
    const float oma = 1.0f - alpha;

    float mem1 = 0.f, mem2 = 0.f, mem3 = 0.f;
    float b1 = 0.01f, b2 = 0.01f, b3 = 0.01f;
    float s1 = 0.f, s2 = 0.f, s3 = 0.f;
    float cnt3 = 0.f;
    int na1 = 0, na2 = 0;                // current lengths of list1/list2

    const float* xr = x + n * FLEN;

    for (int t = 0; t < TSTEPS; ++t) {
        // ---- G1: all 8 groups gather s1_old @ Wh1^T -> part[0] ----
        {
            int ch = (na1 + 7) >> 3;
            int lo = g * ch; lo = lo < na1 ? lo : na1;
            int hi = lo + ch; hi = hi < na1 ? hi : na1;
            part[0][g][u] = gatherq(WT1q, list1, lo, hi);
        }
        __syncthreads();                                        // B1
        unsigned long long ball = 0;
        if (upd) {
            // ---- layer-1 update ----
            int base = (t < 48) ? (4 * t) : (FLEN - 4);
            float4 xv = *reinterpret_cast<const float4*>(xr + base);
            float mk1 = m1T[t * H + j];
            float h1 = wi.x * xv.x + wi.y * xv.y + wi.z * xv.z + wi.w * xv.w
                     + bs1 + sumg((const float*)&part[0][0][0], j, 8);
            b1 = ro1 * b1 + omr1 * s1;
            float Bth = 0.01f + 1.8f * b1;
            float nm = mem1 * alpha + oma * h1 - Bth * s1;
            mem1 = (mk1 == 0.0f) ? mem1 : nm;
            s1 = (mem1 - Bth > 0.0f) ? mk1 : 0.0f;
            ball = __ballot(s1 != 0.0f);
            if (lane == 0) wcnt[wid8] = __popcll(ball);
        } else {
            // ---- overlapped: s2_old @ Wh2^T (groups 4..7, quarters) ----
            int ch = (na2 + 3) >> 2;
            int lo = q4 * ch; lo = lo < na2 ? lo : na2;
            int hi = lo + ch; hi = hi < na2 ? hi : na2;
            pH[q4][u] = gatherq(WTh2q, list2, lo, hi);
        }
        __syncthreads();                                        // B2
        {
            int basew = 0, tot = 0;
#pragma unroll
            for (int w = 0; w < 8; ++w) {
                int c = wcnt[w];
                if (w < wid8) basew += c;
                tot += c;
            }
            if (upd && s1 != 0.0f) {
                int pre = __popcll(ball & ((1ull << lane) - 1ull));
                list1[basew + pre] = j << 9;
            }
            na1 = tot;
        }
        __syncthreads();                                        // B3

        // ---- G2: all 8 groups gather s1_new @ Wi2^T -> part[1] ----
        {
            int ch = (na1 + 7) >> 3;
            int lo = g * ch; lo = lo < na1 ? lo : na1;
            int hi = lo + ch; hi = hi < na1 ? hi : na1;
            part[1][g][u] = gatherq(WTi2q, list1, lo, hi);
        }
        __syncthreads();                                        // B4
        if (upd) {
            // ---- layer-2 update ----
            float mk2 = m2T[t * H + j];
            float h2 = bs2 + sumg((const float*)&part[1][0][0], j, 8)
                           + sumg((const float*)&pH[0][0], j, 4);
            b2 = ro2 * b2 + omr2 * s2;
            float Bth = 0.01f + 1.8f * b2;
            float nm = mem2 * alpha + oma * h2 - Bth * s2;
            mem2 = (mk2 == 0.0f) ? mem2 : nm;
            s2 = (mem2 - Bth > 0.0f) ? mk2 : 0.0f;
            ball = __ballot(s2 != 0.0f);
            if (lane == 0) wcnt[wid8] = __popcll(ball);
        }
        __syncthreads();                                        // B5
        {
            int basew = 0, tot = 0;
#pragma unroll
            for (int w = 0; w < 8; ++w) {
                int c = wcnt[w];
                if (w < wid8) basew += c;
                tot += c;
            }
            if (upd && s2 != 0.0f) {
                int pre = __popcll(ball & ((1ull << lane) - 1ull));
                list2[basew + pre] = j << 9;
            }
            na2 = tot;
        }
        __syncthreads();                                        // B6

        // ---- G3: all 8 groups gather s2_new @ Wi3^T -> part[2] ----
        {
            int ch = (na2 + 7) >> 3;
            int lo = g * ch; lo = lo < na2 ? lo : na2;
            int hi = lo + ch; hi = hi < na2 ? hi : na2;
            part[2][g][u] = gatherq(WTi3q, list2, lo, hi);
        }
        __syncthreads();                                        // B7
        if (upd) {
            // ---- layer-3 update ----
            float mk3 = m3T[t * H + j];
            float h3 = bs3 + sumg((const float*)&part[2][0][0], j, 8);
            b3 = ro3 * b3 + omr3 * s3;
            float Bth = 0.01f + 1.8f * b3;
            float nm = mem3 * alpha + oma * h3 - Bth * s3;
            mem3 = (mk3 == 0.0f) ? mem3 : nm;
            s3 = (mem3 - Bth > 0.0f) ? mk3 : 0.0f;
            cnt3 += s3;   // defer output GEMV
        }
        // next G1 writes part[0]: its last read (L1 update) was before B2;
        // helpers reach next G1 only after this step's B7 -> safe.
    }

    // ---- output: out[n,o] = (Wo[o,:]·cnt3 + T*bo[o]) / T ----
    __syncthreads();
    float* c3 = (float*)&part[0][0][0];
    if (upd) c3[j] = cnt3;
    __syncthreads();
    int wv = tid >> 6;   // 0..15
    for (int o = wv; o < 10; o += 16) {
        float p = 0.0f;
        for (int i = lane; i < H; i += 64)
            p += Wo[o * H + i] * c3[i];
        for (int off = 32; off > 0; off >>= 1)
            p += __shfl_down(p, off);
        if (lane == 0)
            out[n * 10 + o] = (p + 196.0f * bo[o]) / 196.0f;
    }
}

extern "C" void kernel_launch(void* const* d_in, const int* in_sizes, int n_in,
                              void* d_out, int out_size, void* d_ws, size_t ws_size,
                              hipStream_t stream)
{
    const float* x    = (const float*)d_in[0];
    const float* Wi1  = (const float*)d_in[1];
    const float* bi1  = (const float*)d_in[2];
    const float* Wh1  = (const float*)d_in[3];
    const float* bh1  = (const float*)d_in[4];
    const float* Wi2  = (const float*)d_in[5];
    const float* bi2  = (const float*)d_in[6];
    const float* Wh2  = (const float*)d_in[7];
    const float* bh2  = (const float*)d_in[8];
    const float* Wi3  = (const float*)d_in[9];
    const float* bi3  = (const float*)d_in[10];
    const float* Wo   = (const float*)d_in[11];
    const float* bo   = (const float*)d_in[12];
    const float* tau1 = (const float*)d_in[13];
    const float* tau2 = (const float*)d_in[14];
    const float* tau3 = (const float*)d_in[15];
    const float* m1   = (const float*)d_in[16];
    const float* m2   = (const float*)d_in[17];
    const float* m3   = (const float*)d_in[18];

    float* ws  = (float*)d_ws;
    float* out = (float*)d_out;

    // pre-pass: transpose the 4 recurrent/ff matrices + 3 masks into ws
    transpose4<<<dim3(16, 16, 4), dim3(32, 8, 1), 0, stream>>>(Wh1, Wi2, Wh2, Wi3, ws);
    maskT3<<<dim3((TSTEPS * H + 255) / 256, 1, 3), 256, 0, stream>>>(m1, m2, m3, ws + 1048576);

    // main persistent kernel: 1 sample per workgroup (256 WGs, 1024 thr, 16 waves)
    lsnn_main<<<NBATCH, 1024, 0, stream>>>(x, Wi1, bi1, bh1, bi2, bh2, bi3,
                                           Wo, bo, tau1, tau2, tau3, ws, out);
}